// Round 6
// baseline (118.965 us; speedup 1.0000x reference)
//
#include <hip/hip_runtime.h>
#include <math.h>

#define HW2   62
#define NANCH 34596   // 62*62*9
#define NBAT  16
#define NGT   8
#define FEATC 256
#define NOUT  45      // 9 cls + 36 box channels

typedef short bf16x8 __attribute__((ext_vector_type(8)));
typedef float f32x4  __attribute__((ext_vector_type(4)));

#define AS1U(p) ((const __attribute__((address_space(1))) unsigned int*)(p))
#define AS3U(p) ((__attribute__((address_space(3))) unsigned int*)(p))

// fp32 -> bf16 round-to-nearest-even
__device__ __forceinline__ unsigned short f2bf(float f) {
    unsigned int u = __float_as_uint(f);
    u = u + 0x7FFFu + ((u >> 16) & 1u);
    return (unsigned short)(u >> 16);
}

// ---------- shared device helpers (bitwise identical to passing R2-R5) ----------

__device__ __forceinline__ void anchor4(int i, int j, int a,
                                        float& x1, float& y1, float& x2, float& y2) {
    int am = a % 3, ad = a / 3;
    float h = 2.f * (float)(am + 1);              // 2,4,6
    float w = h * 0.5f * (float)(1 << ad);        // h*{0.5,1,2}
    float cx = (float)i + 0.5f, cy = (float)j + 0.5f;
    x1 = fminf(fmaxf(cx - 0.5f * w, 0.f), 62.f);
    x2 = fminf(fmaxf(cx + 0.5f * w, 0.f), 62.f);
    y1 = fminf(fmaxf(cy - 0.5f * h, 0.f), 62.f);
    y2 = fminf(fmaxf(cy + 0.5f * h, 0.f), 62.f);
}

__device__ __forceinline__ float iou_fn(float ax1, float ay1, float ax2, float ay2,
                                        float gx1, float gy1, float gx2, float gy2) {
    float area_a = __fmul_rn(__fsub_rn(ax2, ax1), __fsub_rn(ay2, ay1));
    float area_g = __fmul_rn(__fsub_rn(gx2, gx1), __fsub_rn(gy2, gy1));
    float ix1 = fmaxf(ax1, gx1), iy1 = fmaxf(ay1, gy1);
    float ix2 = fminf(ax2, gx2), iy2 = fminf(ay2, gy2);
    float iw = fmaxf(__fsub_rn(ix2, ix1), 0.f);
    float ih = fmaxf(__fsub_rn(iy2, iy1), 0.f);
    float inter = __fmul_rn(iw, ih);
    float uni = __fsub_rn(__fadd_rn(area_a, area_g), inter);
    return inter / fmaxf(uni, 1e-9f);
}

__device__ __forceinline__ float softplus_f(float x) {
    return fmaxf(x, 0.f) + log1pf(expf(-fabsf(x)));
}

__device__ __forceinline__ float sl1_f(float d) {
    float ad = fabsf(d);
    return (ad < 1.f) ? 0.5f * d * d : (ad - 0.5f);
}

// ---------- Kernel 1: fold partials (R2-proven), zero counter ----------
__global__ void fold_part(const float* __restrict__ conv_w,
                          const float* __restrict__ cls_w,
                          const float* __restrict__ box_w,
                          float* __restrict__ partial,
                          unsigned int* __restrict__ counter) {
    if (blockIdx.x == 0 && blockIdx.y == 0 && threadIdx.x == 0) *counter = 0u;
    __shared__ float w2s[64][45];
    int g = blockIdx.y, t = threadIdx.x;
    for (int i = t; i < 64 * 45; i += 256) {
        int m = i / 45, o = i - m * 45;
        w2s[m][o] = (o < 9) ? cls_w[o * FEATC + g * 64 + m]
                            : box_w[(o - 9) * FEATC + g * 64 + m];
    }
    __syncthreads();
    int idx = blockIdx.x * 256 + t;
    float acc[NOUT];
#pragma unroll
    for (int o = 0; o < NOUT; ++o) acc[o] = 0.f;
    for (int m = 0; m < 64; ++m) {
        float cw = conv_w[(size_t)(g * 64 + m) * 2304 + idx];   // coalesced
#pragma unroll
        for (int o = 0; o < NOUT; ++o)
            acc[o] = fmaf(cw, w2s[m][o], acc[o]);
    }
#pragma unroll
    for (int o = 0; o < NOUT; ++o)
        partial[(size_t)(g * NOUT + o) * 2304 + idx] = acc[o];
}

// ---------- Kernel 2: combine -> Bfrag (chunk-major) | gt max-iou | effb ----------
__global__ void prep2(const float* __restrict__ partial,
                      const float* __restrict__ conv_b,
                      const float* __restrict__ cls_b,
                      const float* __restrict__ box_b,
                      const float* __restrict__ cls_w,
                      const float* __restrict__ box_w,
                      const float* __restrict__ gtb,
                      unsigned short* __restrict__ Bfrag,
                      float* __restrict__ effb,
                      float* __restrict__ maxiou) {
    __shared__ float red[256];
    int blk = blockIdx.x, t = threadIdx.x;
    if (blk < 432) {
        int i = blk * 256 + t;               // < 110592 = 48*2304
        int o = i / 2304, idx = i - o * 2304;
        float s = 0.f;
        if (o < NOUT) {
#pragma unroll
            for (int g = 0; g < 4; ++g)
                s += partial[(size_t)(g * NOUT + o) * 2304 + idx];
        }
        int c = idx / 9, tap = idx - c * 9;
        size_t slot = (((size_t)(c >> 5) * 9 + tap) * 3 + (o >> 4)) * 512
                    + (size_t)((((c >> 3) & 3) * 16) + (o & 15)) * 8 + (c & 7);
        Bfrag[slot] = f2bf(s);
    } else if (blk < 560) {
        int bg = blk - 432;
        int b = bg >> 3, g = bg & 7;
        const float* p = gtb + (b * NGT + g) * 4;
        float gx1 = p[0] * 0.125f, gy1 = p[1] * 0.125f;
        float gx2 = p[2] * 0.125f, gy2 = p[3] * 0.125f;
        float m = 0.f;
        for (int n = t; n < NANCH; n += 256) {
            int i = n / 558; int r = n - i * 558; int j = r / 9; int a = r - j * 9;
            float ax1, ay1, ax2, ay2;
            anchor4(i, j, a, ax1, ay1, ax2, ay2);
            m = fmaxf(m, iou_fn(ax1, ay1, ax2, ay2, gx1, gy1, gx2, gy2));
        }
        red[t] = m;
        __syncthreads();
        for (int s = 128; s > 0; s >>= 1) {
            if (t < s) red[t] = fmaxf(red[t], red[t + s]);
            __syncthreads();
        }
        if (t == 0) maxiou[bg] = red[0];
    } else {
        if (t < 48) {
            float bv = 0.f;
            if (t < NOUT) {
                bv = (t < 9) ? cls_b[t] : box_b[t - 9];
                const float* w2 = (t < 9) ? (cls_w + t * FEATC) : (box_w + (t - 9) * FEATC);
                for (int mid = 0; mid < FEATC; ++mid) bv = fmaf(w2[mid], conv_b[mid], bv);
            }
            effb[t] = bv;
        }
    }
}

// ---------- Kernel 3: features fp32 NCHW -> bf16 [b][cc][cg][y][x][8ch] ----------
// grid (32 y-pairs, 8 cc, g batch), 256 threads
__global__ void to_bf16(const float* __restrict__ feat,
                        unsigned short* __restrict__ ft, int b_base) {
    __shared__ float ldsT[32 * 2 * 64];   // [ch][y][x], x XOR-swizzled by ch
    int yp = blockIdx.x, cc = blockIdx.y, bz = blockIdx.z;
    int b = b_base + bz;
    int y0 = yp * 2, t = threadIdx.x;
#pragma unroll
    for (int k = 0; k < 4; ++k) {
        int fi = k * 256 + t;
        int ch = fi >> 5, r = fi & 31;
        int y = r >> 4, xq = r & 15;
        f32x4 v = *(const f32x4*)(feat + ((size_t)(b * 256 + cc * 32 + ch) << 12)
                                  + (y0 + y) * 64 + xq * 4);
        int word = ch * 128 + y * 64 + ((xq * 4) ^ ((ch & 7) << 3));
        *(f32x4*)(ldsT + word) = v;
    }
    __syncthreads();
    int y = t >> 7, x = (t >> 1) & 63, h2 = t & 1;
    bf16x8 o0, o1;
#pragma unroll
    for (int j = 0; j < 8; ++j) {
        int ch = h2 * 16 + j;
        o0[j] = (short)f2bf(ldsT[ch * 128 + y * 64 + (x ^ ((ch & 7) << 3))]);
    }
#pragma unroll
    for (int j = 0; j < 8; ++j) {
        int ch = h2 * 16 + 8 + j;
        o1[j] = (short)f2bf(ldsT[ch * 128 + y * 64 + (x ^ ((ch & 7) << 3))]);
    }
    unsigned short* ftc = ft + ((size_t)(bz * 8 + cc) << 17);
    size_t p = (size_t)(y0 + y) * 64 + x;
    *(bf16x8*)(ftc + ((size_t)(h2 * 2) * 4096 + p) * 8) = o0;
    *(bf16x8*)(ftc + ((size_t)(h2 * 2 + 1) * 4096 + p) * 8) = o1;
}

// ---------- Kernel 4: MFMA conv (global_load_lds staged) + fused epilogue/finalize ----------
// grid (31 bands of 2 rows, g batch), 256 threads (4 waves).
// Wave w: 2 m-frags (pixels w*32..w*32+31) x 3 n-frags; 8 K-chunks of 32 ch.
// LDS: A [cg][256pix][8ch] 16 KB + B 27.6 KB, single-buffered -> 3 blocks/CU.
__launch_bounds__(256, 3)
__global__ void conv_fused(const unsigned short* __restrict__ ft,
                           const unsigned short* __restrict__ Bfrag,
                           const float* __restrict__ effb,
                           const float* __restrict__ gtb,
                           const int* __restrict__ gtc,
                           const float* __restrict__ maxiou,
                           float* __restrict__ outp,
                           float* __restrict__ blksums,
                           unsigned int* __restrict__ counter,
                           int b_base) {
    __shared__ __align__(16) unsigned char smem[44032];  // A [0,16384) | B [16384,44032)
    __shared__ float gshr[40];
    __shared__ float tot[5];
    __shared__ unsigned int lastflag;

    float* red = (float*)smem;                       // overlay [0,1024) after K-loop
    float (*Cs)[49] = (float (*)[49])(smem + 2048);  // overlay [2048,26352) after K-loop

    const int t = threadIdx.x, l = t & 63, w = t >> 6;
    const int band = blockIdx.x, bz = blockIdx.y, b = b_base + bz;
    const int l15 = l & 15, lq = l >> 4;
    const int y0 = band * 2;

    if (t < 32) gshr[t] = gtb[b * 32 + t] * 0.125f;
    else if (t < 40) gshr[t] = maxiou[b * 8 + (t - 32)];

    f32x4 acc[2][3];
#pragma unroll
    for (int nf = 0; nf < 3; ++nf) {
        float bv = effb[nf * 16 + l15];
#pragma unroll
        for (int mf = 0; mf < 2; ++mf)
#pragma unroll
            for (int r = 0; r < 4; ++r) acc[mf][nf][r] = bv;
    }

    // A-frag pixel bases (clamped for pad pixels 124..127)
    int p0 = w * 32 + l15;      if (p0 > 123) p0 = 123;
    int p1 = w * 32 + 16 + l15; if (p1 > 123) p1 = 123;
    int rr0 = p0 / 62, c0 = p0 - rr0 * 62;
    int rr1 = p1 / 62, c1 = p1 - rr1 * 62;
    const int ab0 = rr0 * 64 + c0;
    const int ab1 = rr1 * 64 + c1;

    auto gload = [&](int cc) {
        const unsigned short* ftc = ft + ((size_t)(bz * 8 + cc) << 17);
#pragma unroll
        for (int k = 0; k < 4; ++k) {                 // A: 1024 units of 16B
            int u = t + k * 256;
            int cg = u >> 8, pix = u & 255;
            const unsigned short* src = ftc + ((size_t)cg * 4096 + (size_t)y0 * 64 + pix) * 8;
            __builtin_amdgcn_global_load_lds(AS1U(src), AS3U(smem + u * 16), 16, 0, 0);
        }
        const unsigned short* Bt = Bfrag + (size_t)cc * 13824;
#pragma unroll
        for (int k = 0; k < 7; ++k) {                 // B: 1728 units of 16B
            int u = t + k * 256;
            if (u < 1728)
                __builtin_amdgcn_global_load_lds(AS1U(Bt + (size_t)u * 8),
                                                 AS3U(smem + 16384 + u * 16), 16, 0, 0);
        }
    };
    auto compute = [&]() {
        const char* base = (const char*)smem;
#pragma unroll
        for (int dy = 0; dy < 3; ++dy)
#pragma unroll
            for (int dx = 0; dx < 3; ++dx) {
                int tap = dy * 3 + dx;
                bf16x8 bfr[3];
#pragma unroll
                for (int nf = 0; nf < 3; ++nf)
                    bfr[nf] = *(const bf16x8*)(base + 16384 + (((tap * 3 + nf) << 6) + l) * 16);
                bf16x8 a0 = *(const bf16x8*)(base + (lq << 12) + (ab0 + dy * 64 + dx) * 16);
                bf16x8 a1 = *(const bf16x8*)(base + (lq << 12) + (ab1 + dy * 64 + dx) * 16);
#pragma unroll
                for (int nf = 0; nf < 3; ++nf) {
                    acc[0][nf] = __builtin_amdgcn_mfma_f32_16x16x32_bf16(a0, bfr[nf], acc[0][nf], 0, 0, 0);
                    acc[1][nf] = __builtin_amdgcn_mfma_f32_16x16x32_bf16(a1, bfr[nf], acc[1][nf], 0, 0, 0);
                }
            }
    };

    // K-loop: single LDS buffer, DMA staging, 2 barriers/chunk (cross-block overlap hides waits)
    gload(0);
    asm volatile("s_waitcnt vmcnt(0)" ::: "memory");
    __syncthreads();
    for (int cc = 0; cc < 8; ++cc) {
        compute();
        __syncthreads();                       // all waves done reading this chunk
        if (cc < 7) {
            gload(cc + 1);
            asm volatile("s_waitcnt vmcnt(0)" ::: "memory");
            __syncthreads();                   // chunk cc+1 resident
        }
    }

    // C fragments -> LDS (overlays staging; safe after last barrier)
#pragma unroll
    for (int mf = 0; mf < 2; ++mf)
#pragma unroll
        for (int nf = 0; nf < 3; ++nf)
#pragma unroll
            for (int r = 0; r < 4; ++r) {
                int pix = w * 32 + mf * 16 + lq * 4 + r;
                if (pix < 124) Cs[pix][nf * 16 + l15] = acc[mf][nf][r];
            }
    __syncthreads();

    // ---- fused per-anchor epilogue: 2x62 pixels x 9 anchors = 1116 anchors ----
    float s_pos = 0.f, s_neg = 0.f, s_pl = 0.f, s_nl = 0.f, s_reg = 0.f;
    float* out_prop = outp + 2;
    float* out_mask = out_prop + (size_t)NBAT * NANCH * 4;
    float* out_gtc  = out_mask + (size_t)NBAT * NANCH * 8;

    for (int k = 0; k < 5; ++k) {
        int an = k * 256 + t;
        if (an < 1116) {
            int pixloc = an / 9, a = an - pixloc * 9;
            int rr = pixloc / 62, col = pixloc - rr * 62;
            int oy = y0 + rr, ox = col;
            {
                int n = oy * 558 + ox * 9 + a;
                float cls = Cs[pixloc][a];
                float p0f = Cs[pixloc][9 + 4 * a];
                float p1f = Cs[pixloc][10 + 4 * a];
                float p2f = Cs[pixloc][11 + 4 * a];
                float p3f = Cs[pixloc][12 + 4 * a];

                float ax1, ay1, ax2, ay2;
                anchor4(oy, ox, a, ax1, ay1, ax2, ay2);
                float aw = ax2 - ax1, ah = ay2 - ay1;
                float acx = 0.5f * (ax1 + ax2), acy = 0.5f * (ay1 + ay2);

                const float ps = 64.f / 62.f;
                float pcx = acx + p0f * aw, pcy = acy + p1f * ah;
                float pw = aw * expf(p2f), ph = ah * expf(p3f);
                size_t pb = ((size_t)b * NANCH + n) * 4;
                out_prop[pb + 0] = (pcx - 0.5f * pw) * ps;
                out_prop[pb + 1] = (pcy - 0.5f * ph) * ps;
                out_prop[pb + 2] = (pcx + 0.5f * pw) * ps;
                out_prop[pb + 3] = (pcy + 0.5f * ph) * ps;

                float law = logf(aw), lah = logf(ah);
                float posf_tot = 0.f, negf_tot = 0.f;
                float best_iou = -1.f; int best_g = 0;
                size_t mb = ((size_t)b * NANCH + n) * 8;
#pragma unroll
                for (int g = 0; g < NGT; ++g) {
                    float gx1 = gshr[g * 4 + 0], gy1 = gshr[g * 4 + 1];
                    float gx2 = gshr[g * 4 + 2], gy2 = gshr[g * 4 + 3];
                    float iou = iou_fn(ax1, ay1, ax2, ay2, gx1, gy1, gx2, gy2);
                    float mpg = gshr[32 + g];
                    bool pm = ((iou == mpg) && (mpg > 0.f)) || (iou > 0.7f);
                    float pf = pm ? 1.f : 0.f;
                    float nf = (iou < 0.3f) ? 1.f : 0.f;
                    out_mask[mb + g] = pf;
                    posf_tot += pf; negf_tot += nf;
                    if (iou > best_iou) { best_iou = iou; best_g = g; }  // first-max-wins
                    if (pm) {
                        float gw = gx2 - gx1, gh = gy2 - gy1;
                        float gcx = 0.5f * (gx1 + gx2), gcy = 0.5f * (gy1 + gy2);
                        float tx_ = (gcx - acx) / aw, ty_ = (gcy - acy) / ah;
                        float tw_ = logf(gw) - law, th_ = logf(gh) - lah;
                        float d0 = p0f - tx_, d1 = p1f - ty_, d2 = p2f - tw_, d3 = p3f - th_;
                        s_reg += sl1_f(d0) + sl1_f(d1) + sl1_f(d2) + sl1_f(d3);
                    }
                }
                s_pos += posf_tot; s_neg += negf_tot;
                s_pl += softplus_f(-cls) * posf_tot;
                s_nl += softplus_f(cls) * negf_tot;
                out_gtc[(size_t)b * NANCH + n] = (float)gtc[b * NGT + best_g];
            }
        }
    }

    // deterministic per-block tree reduction of the 5 loss partials
    int blk = b * 31 + band;   // nblk = 496
    float vals[5] = {s_pos, s_neg, s_pl, s_nl, s_reg};
#pragma unroll
    for (int s = 0; s < 5; ++s) {
        red[t] = vals[s];
        __syncthreads();
        for (int st = 128; st > 0; st >>= 1) {
            if (t < st) red[t] += red[t + st];
            __syncthreads();
        }
        if (t == 0) blksums[(size_t)s * 496 + blk] = red[0];
        __syncthreads();
    }

    // fused finalize: last block (fence+atomic) does the fixed-order reduce
    if (t == 0) {
        __threadfence();
        lastflag = (atomicAdd(counter, 1u) == 495u) ? 1u : 0u;
    }
    __syncthreads();
    if (lastflag) {
        __threadfence();
#pragma unroll
        for (int s = 0; s < 5; ++s) {
            float a = 0.f;
            for (int i = t; i < 496; i += 256) a += blksums[(size_t)s * 496 + i];
            red[t] = a;
            __syncthreads();
            for (int st = 128; st > 0; st >>= 1) {
                if (t < st) red[t] += red[t + st];
                __syncthreads();
            }
            if (t == 0) tot[s] = red[0];
            __syncthreads();
        }
        if (t == 0) {
            float np_ = fmaxf(tot[0], 1.f), nn_ = fmaxf(tot[1], 1.f);
            outp[0] = 0.5f * (tot[2] / np_ + tot[3] / nn_);  // cls_loss
            outp[1] = tot[4] / (np_ * 4.f);                  // reg_loss
        }
    }
}

extern "C" void kernel_launch(void* const* d_in, const int* in_sizes, int n_in,
                              void* d_out, int out_size, void* d_ws, size_t ws_size,
                              hipStream_t stream) {
    (void)in_sizes; (void)n_in; (void)out_size;
    const float* feat   = (const float*)d_in[0];
    const float* gtb    = (const float*)d_in[1];
    const int*   gtc    = (const int*)d_in[2];
    const float* conv_w = (const float*)d_in[3];
    const float* conv_b = (const float*)d_in[4];
    const float* cls_w  = (const float*)d_in[5];
    const float* cls_b  = (const float*)d_in[6];
    const float* box_w  = (const float*)d_in[7];
    const float* box_b  = (const float*)d_in[8];
    float* outp = (float*)d_out;
    float* ws   = (float*)d_ws;

    // workspace layout (floats)
    unsigned short* Bfrag   = (unsigned short*)ws;            // 110592 us = 55296 fl
    float*          effb    = ws + 55296;                     // 64
    float*          maxiou  = ws + 55360;                     // 128
    unsigned int*   counter = (unsigned int*)(ws + 55488);    // 64
    float*          blksums = ws + 55552;                     // 5*496 -> pad 2560
    float*          partial = ws + 58112;                     // 4*45*2304 = 414720
    unsigned short* ft      = (unsigned short*)(ws + 472832); // g * 1048576 ushorts

    // batch-group size: largest g in {16,8,4,2,1} that fits the workspace
    size_t avail = ws_size / 4;
    int g = 16;
    while (g > 1 && (size_t)472832 + (size_t)g * 524288 > avail) g >>= 1;

    fold_part<<<dim3(9, 4), 256, 0, stream>>>(conv_w, cls_w, box_w, partial, counter);
    prep2<<<561, 256, 0, stream>>>(partial, conv_b, cls_b, box_b, cls_w, box_w, gtb,
                                   Bfrag, effb, maxiou);
    for (int b0 = 0; b0 < NBAT; b0 += g) {
        to_bf16<<<dim3(32, 8, g), 256, 0, stream>>>(feat, ft, b0);
        conv_fused<<<dim3(31, g), 256, 0, stream>>>(ft, Bfrag, effb, gtb, gtc, maxiou,
                                                    outp, blksums, counter, b0);
    }
}

// Round 7
// 84.180 us; speedup vs baseline: 1.4132x; 1.4132x over previous
//
#include <hip/hip_runtime.h>
#include <math.h>

#define HW2   62
#define NANCH 34596   // 62*62*9
#define NBAT  16
#define NGT   8
#define FEATC 256
#define NOUT  45      // 9 cls + 36 box channels

typedef short bf16x8 __attribute__((ext_vector_type(8)));
typedef float f32x4  __attribute__((ext_vector_type(4)));

#define AS1U(p) ((const __attribute__((address_space(1))) unsigned int*)(p))
#define AS3U(p) ((__attribute__((address_space(3))) unsigned int*)(p))

// fp32 -> bf16 round-to-nearest-even
__device__ __forceinline__ unsigned short f2bf(float f) {
    unsigned int u = __float_as_uint(f);
    u = u + 0x7FFFu + ((u >> 16) & 1u);
    return (unsigned short)(u >> 16);
}

// ---------- shared device helpers (bitwise identical to passing R2-R6) ----------

__device__ __forceinline__ void anchor4(int i, int j, int a,
                                        float& x1, float& y1, float& x2, float& y2) {
    int am = a % 3, ad = a / 3;
    float h = 2.f * (float)(am + 1);              // 2,4,6
    float w = h * 0.5f * (float)(1 << ad);        // h*{0.5,1,2}
    float cx = (float)i + 0.5f, cy = (float)j + 0.5f;
    x1 = fminf(fmaxf(cx - 0.5f * w, 0.f), 62.f);
    x2 = fminf(fmaxf(cx + 0.5f * w, 0.f), 62.f);
    y1 = fminf(fmaxf(cy - 0.5f * h, 0.f), 62.f);
    y2 = fminf(fmaxf(cy + 0.5f * h, 0.f), 62.f);
}

__device__ __forceinline__ float iou_fn(float ax1, float ay1, float ax2, float ay2,
                                        float gx1, float gy1, float gx2, float gy2) {
    float area_a = __fmul_rn(__fsub_rn(ax2, ax1), __fsub_rn(ay2, ay1));
    float area_g = __fmul_rn(__fsub_rn(gx2, gx1), __fsub_rn(gy2, gy1));
    float ix1 = fmaxf(ax1, gx1), iy1 = fmaxf(ay1, gy1);
    float ix2 = fminf(ax2, gx2), iy2 = fminf(ay2, gy2);
    float iw = fmaxf(__fsub_rn(ix2, ix1), 0.f);
    float ih = fmaxf(__fsub_rn(iy2, iy1), 0.f);
    float inter = __fmul_rn(iw, ih);
    float uni = __fsub_rn(__fadd_rn(area_a, area_g), inter);
    return inter / fmaxf(uni, 1e-9f);
}

__device__ __forceinline__ float softplus_f(float x) {
    return fmaxf(x, 0.f) + log1pf(expf(-fabsf(x)));
}

__device__ __forceinline__ float sl1_f(float d) {
    float ad = fabsf(d);
    return (ad < 1.f) ? 0.5f * d * d : (ad - 0.5f);
}

// ---------- to_bf16 body: fp32 NCHW -> bf16 [b][cc][cg][y][x][8ch] ----------
__device__ __forceinline__ void to_bf16_body(const float* __restrict__ feat,
                                             unsigned short* __restrict__ ft,
                                             float* ldsT,
                                             int yp, int cc, int bz, int b, int t) {
    int y0 = yp * 2;
#pragma unroll
    for (int k = 0; k < 4; ++k) {
        int fi = k * 256 + t;
        int ch = fi >> 5, r = fi & 31;
        int y = r >> 4, xq = r & 15;
        f32x4 v = *(const f32x4*)(feat + ((size_t)(b * 256 + cc * 32 + ch) << 12)
                                  + (y0 + y) * 64 + xq * 4);
        int word = ch * 128 + y * 64 + ((xq * 4) ^ ((ch & 7) << 3));
        *(f32x4*)(ldsT + word) = v;
    }
    __syncthreads();
    int y = t >> 7, x = (t >> 1) & 63, h2 = t & 1;
    bf16x8 o0, o1;
#pragma unroll
    for (int j = 0; j < 8; ++j) {
        int ch = h2 * 16 + j;
        o0[j] = (short)f2bf(ldsT[ch * 128 + y * 64 + (x ^ ((ch & 7) << 3))]);
    }
#pragma unroll
    for (int j = 0; j < 8; ++j) {
        int ch = h2 * 16 + 8 + j;
        o1[j] = (short)f2bf(ldsT[ch * 128 + y * 64 + (x ^ ((ch & 7) << 3))]);
    }
    unsigned short* ftc = ft + ((size_t)(bz * 8 + cc) << 17);
    size_t p = (size_t)(y0 + y) * 64 + x;
    *(bf16x8*)(ftc + ((size_t)(h2 * 2) * 4096 + p) * 8) = o0;
    *(bf16x8*)(ftc + ((size_t)(h2 * 2 + 1) * 4096 + p) * 8) = o1;
}

// ---------- Kernel 1: prep_all (fold | gt max-iou | effb+counter | to_bf16) ----------
// blocks [0,432): Bfrag direct fold (R4-proven); [432,560): gt max; [560]: effb;
// [561, 561+256*g0): to_bf16 for batch group [0, g0)
__global__ void prep_all(const float* __restrict__ feat,
                         const float* __restrict__ conv_w,
                         const float* __restrict__ conv_b,
                         const float* __restrict__ cls_w,
                         const float* __restrict__ cls_b,
                         const float* __restrict__ box_w,
                         const float* __restrict__ box_b,
                         const float* __restrict__ gtb,
                         unsigned short* __restrict__ Bfrag,
                         float* __restrict__ effb,
                         float* __restrict__ maxiou,
                         unsigned int* __restrict__ counter,
                         unsigned short* __restrict__ ft) {
    __shared__ float ldsT[4096];
    __shared__ float red[256];
    int blk = blockIdx.x, t = threadIdx.x;
    if (blk < 432) {
        int i = blk * 256 + t;               // < 110592 = 48*2304
        int o = i / 2304, idx = i - o * 2304;
        float s = 0.f;
        if (o < NOUT) {
            const float* w2 = (o < 9) ? (cls_w + o * FEATC) : (box_w + (o - 9) * FEATC);
#pragma unroll 8
            for (int m = 0; m < FEATC; ++m)
                s = fmaf(w2[m], conv_w[(size_t)m * 2304 + idx], s);  // w2 uniform, conv_w coalesced
        }
        int c = idx / 9, tap = idx - c * 9;
        size_t slot = (((size_t)(c >> 5) * 9 + tap) * 3 + (o >> 4)) * 512
                    + (size_t)((((c >> 3) & 3) * 16) + (o & 15)) * 8 + (c & 7);
        Bfrag[slot] = f2bf(s);
    } else if (blk < 560) {
        int bg = blk - 432;
        int b = bg >> 3, g = bg & 7;
        const float* p = gtb + (b * NGT + g) * 4;
        float gx1 = p[0] * 0.125f, gy1 = p[1] * 0.125f;
        float gx2 = p[2] * 0.125f, gy2 = p[3] * 0.125f;
        float m = 0.f;
        for (int n = t; n < NANCH; n += 256) {
            int i = n / 558; int r = n - i * 558; int j = r / 9; int a = r - j * 9;
            float ax1, ay1, ax2, ay2;
            anchor4(i, j, a, ax1, ay1, ax2, ay2);
            m = fmaxf(m, iou_fn(ax1, ay1, ax2, ay2, gx1, gy1, gx2, gy2));
        }
        red[t] = m;
        __syncthreads();
        for (int s = 128; s > 0; s >>= 1) {
            if (t < s) red[t] = fmaxf(red[t], red[t + s]);
            __syncthreads();
        }
        if (t == 0) maxiou[bg] = red[0];
    } else if (blk == 560) {
        if (t == 0) *counter = 0u;
        if (t < 48) {
            float bv = 0.f;
            if (t < NOUT) {
                bv = (t < 9) ? cls_b[t] : box_b[t - 9];
                const float* w2 = (t < 9) ? (cls_w + t * FEATC) : (box_w + (t - 9) * FEATC);
                for (int mid = 0; mid < FEATC; ++mid) bv = fmaf(w2[mid], conv_b[mid], bv);
            }
            effb[t] = bv;
        }
    } else {
        int u = blk - 561;
        int yp = u & 31, cc = (u >> 5) & 7, bz = u >> 8;
        to_bf16_body(feat, ft, ldsT, yp, cc, bz, bz, t);
    }
}

// ---------- standalone to_bf16 for fallback batch groups ----------
__global__ void to_bf16(const float* __restrict__ feat,
                        unsigned short* __restrict__ ft, int b_base) {
    __shared__ float ldsT[4096];
    to_bf16_body(feat, ft, ldsT, blockIdx.x, blockIdx.y, blockIdx.z,
                 b_base + blockIdx.z, threadIdx.x);
}

// ---------- Kernel 2: MFMA conv (A direct-global, B LDS-dbuf) + epilogue + finalize ----------
// 1D grid nwg = 31*g blocks (bijective XCD swizzle), 256 threads (4 waves).
// Band = 2 output rows (124 pixels). Wave w: pixels w*32..w*32+31 (2 m-frags) x 3 n-frags.
// 8 K-chunks of 32 ch; B double-buffered via global_load_lds, ONE barrier per chunk.
__launch_bounds__(256, 2)
__global__ void conv_fused(const unsigned short* __restrict__ ft,
                           const unsigned short* __restrict__ Bfrag,
                           const float* __restrict__ effb,
                           const float* __restrict__ gtb,
                           const int* __restrict__ gtc,
                           const float* __restrict__ maxiou,
                           float* __restrict__ outp,
                           float* __restrict__ blksums,
                           unsigned int* __restrict__ counter,
                           int b_base) {
    __shared__ __align__(16) unsigned char smem[55296];  // B dbuf 2 x 27648; Cs overlays
    __shared__ float gshr[40];
    __shared__ float redl[256];
    __shared__ float tot[5];
    __shared__ unsigned int lastflag;

    float (*Cs)[49] = (float (*)[49])smem;   // 124*49*4 = 24304 B, after K-loop

    const int t = threadIdx.x, l = t & 63, w = t >> 6;
    const int l15 = l & 15, lq = l >> 4;

    // bijective XCD swizzle (m204): each XCD gets a contiguous wgid chunk
    int nwg = gridDim.x;
    int q = nwg >> 3, r = nwg & 7;
    int xcd = blockIdx.x & 7, within = blockIdx.x >> 3;
    int wgid = ((xcd < r) ? xcd * (q + 1) : r * (q + 1) + (xcd - r) * q) + within;
    const int band = wgid % 31, bz = wgid / 31;
    const int b = b_base + bz;
    const int y0 = band * 2;

    if (t < 32) gshr[t] = gtb[b * 32 + t] * 0.125f;
    else if (t < 40) gshr[t] = maxiou[b * 8 + (t - 32)];

    f32x4 acc[2][3];
#pragma unroll
    for (int nf = 0; nf < 3; ++nf) {
        float bv = effb[nf * 16 + l15];
#pragma unroll
        for (int mf = 0; mf < 2; ++mf)
#pragma unroll
            for (int r2 = 0; r2 < 4; ++r2) acc[mf][nf][r2] = bv;
    }

    // per-thread A base offsets (16B units) into ft chunk; clamp pad pixels
    int p0 = w * 32 + l15;      if (p0 > 123) p0 = 123;
    int p1 = w * 32 + 16 + l15; if (p1 > 123) p1 = 123;
    int rr0 = p0 / 62, c0 = p0 - rr0 * 62;
    int rr1 = p1 / 62, c1 = p1 - rr1 * 62;
    const int aoff0 = (lq << 12) + (y0 + rr0) * 64 + c0;
    const int aoff1 = (lq << 12) + (y0 + rr1) * 64 + c1;

    auto loadB = [&](int cc, int buf) {
        const unsigned short* Bt = Bfrag + (size_t)cc * 13824;
#pragma unroll
        for (int k = 0; k < 7; ++k) {                 // 1728 units of 16B
            int u = t + k * 256;
            if (u < 1728)
                __builtin_amdgcn_global_load_lds(AS1U(Bt + (size_t)u * 8),
                                                 AS3U(smem + buf * 27648 + u * 16), 16, 0, 0);
        }
    };
    auto computeChunk = [&](int cc, int buf) {
        const unsigned short* ftc = ft + ((size_t)(bz * 8 + cc) << 17);
        // hoist all 18 A-fragment loads to chunk start (latency hidden under MFMAs)
        bf16x8 A0[9], A1[9];
#pragma unroll
        for (int tap = 0; tap < 9; ++tap) {
            int d = (tap / 3) * 64 + (tap % 3);
            A0[tap] = *(const bf16x8*)(ftc + (size_t)(aoff0 + d) * 8);
            A1[tap] = *(const bf16x8*)(ftc + (size_t)(aoff1 + d) * 8);
        }
        const char* Bb = (const char*)smem + buf * 27648;
#pragma unroll
        for (int tap = 0; tap < 9; ++tap) {
#pragma unroll
            for (int nf = 0; nf < 3; ++nf) {
                bf16x8 bfr = *(const bf16x8*)(Bb + (((tap * 3 + nf) << 6) + l) * 16);
                acc[0][nf] = __builtin_amdgcn_mfma_f32_16x16x32_bf16(A0[tap], bfr, acc[0][nf], 0, 0, 0);
                acc[1][nf] = __builtin_amdgcn_mfma_f32_16x16x32_bf16(A1[tap], bfr, acc[1][nf], 0, 0, 0);
            }
        }
    };

    // K-loop: B dbuf, one barrier per chunk; next-B DMA drain hides under compute
    loadB(0, 0);
    __syncthreads();
    for (int cc = 0; cc < 8; ++cc) {
        if (cc < 7) loadB(cc + 1, (cc + 1) & 1);
        computeChunk(cc, cc & 1);
        __syncthreads();   // drains vmcnt (next-B landed) + all waves done with this buf
    }

    // C fragments -> LDS (overlays B buffers; safe after final barrier)
#pragma unroll
    for (int mf = 0; mf < 2; ++mf)
#pragma unroll
        for (int nf = 0; nf < 3; ++nf)
#pragma unroll
            for (int r2 = 0; r2 < 4; ++r2) {
                int pix = w * 32 + mf * 16 + lq * 4 + r2;
                if (pix < 124) Cs[pix][nf * 16 + l15] = acc[mf][nf][r2];
            }
    __syncthreads();

    // ---- fused per-anchor epilogue: 2x62 pixels x 9 anchors = 1116 anchors ----
    float s_pos = 0.f, s_neg = 0.f, s_pl = 0.f, s_nl = 0.f, s_reg = 0.f;
    float* out_prop = outp + 2;
    float* out_mask = out_prop + (size_t)NBAT * NANCH * 4;
    float* out_gtc  = out_mask + (size_t)NBAT * NANCH * 8;

    for (int k = 0; k < 5; ++k) {
        int an = k * 256 + t;
        if (an < 1116) {
            int pixloc = an / 9, a = an - pixloc * 9;
            int rr = pixloc / 62, col = pixloc - rr * 62;
            int oy = y0 + rr, ox = col;
            int n = oy * 558 + ox * 9 + a;
            float cls = Cs[pixloc][a];
            float p0f = Cs[pixloc][9 + 4 * a];
            float p1f = Cs[pixloc][10 + 4 * a];
            float p2f = Cs[pixloc][11 + 4 * a];
            float p3f = Cs[pixloc][12 + 4 * a];

            float ax1, ay1, ax2, ay2;
            anchor4(oy, ox, a, ax1, ay1, ax2, ay2);
            float aw = ax2 - ax1, ah = ay2 - ay1;
            float acx = 0.5f * (ax1 + ax2), acy = 0.5f * (ay1 + ay2);

            const float ps = 64.f / 62.f;
            float pcx = acx + p0f * aw, pcy = acy + p1f * ah;
            float pw = aw * expf(p2f), ph = ah * expf(p3f);
            f32x4 prop = { (pcx - 0.5f * pw) * ps, (pcy - 0.5f * ph) * ps,
                           (pcx + 0.5f * pw) * ps, (pcy + 0.5f * ph) * ps };
            *(f32x4*)(out_prop + ((size_t)b * NANCH + n) * 4) = prop;

            float law = logf(aw), lah = logf(ah);
            float posf_tot = 0.f, negf_tot = 0.f;
            float best_iou = -1.f; int best_g = 0;
            float pfv[8];
#pragma unroll
            for (int g = 0; g < NGT; ++g) {
                float gx1 = gshr[g * 4 + 0], gy1 = gshr[g * 4 + 1];
                float gx2 = gshr[g * 4 + 2], gy2 = gshr[g * 4 + 3];
                float iou = iou_fn(ax1, ay1, ax2, ay2, gx1, gy1, gx2, gy2);
                float mpg = gshr[32 + g];
                bool pm = ((iou == mpg) && (mpg > 0.f)) || (iou > 0.7f);
                float pf = pm ? 1.f : 0.f;
                float nf = (iou < 0.3f) ? 1.f : 0.f;
                pfv[g] = pf;
                posf_tot += pf; negf_tot += nf;
                if (iou > best_iou) { best_iou = iou; best_g = g; }  // first-max-wins
                if (pm) {
                    float gw = gx2 - gx1, gh = gy2 - gy1;
                    float gcx = 0.5f * (gx1 + gx2), gcy = 0.5f * (gy1 + gy2);
                    float tx_ = (gcx - acx) / aw, ty_ = (gcy - acy) / ah;
                    float tw_ = logf(gw) - law, th_ = logf(gh) - lah;
                    float d0 = p0f - tx_, d1 = p1f - ty_, d2 = p2f - tw_, d3 = p3f - th_;
                    s_reg += sl1_f(d0) + sl1_f(d1) + sl1_f(d2) + sl1_f(d3);
                }
            }
            size_t mb = ((size_t)b * NANCH + n) * 8;
            f32x4 m0 = { pfv[0], pfv[1], pfv[2], pfv[3] };
            f32x4 m1 = { pfv[4], pfv[5], pfv[6], pfv[7] };
            *(f32x4*)(out_mask + mb) = m0;
            *(f32x4*)(out_mask + mb + 4) = m1;
            s_pos += posf_tot; s_neg += negf_tot;
            s_pl += softplus_f(-cls) * posf_tot;
            s_nl += softplus_f(cls) * negf_tot;
            out_gtc[(size_t)b * NANCH + n] = (float)gtc[b * NGT + best_g];
        }
    }

    // deterministic per-block tree reduction of the 5 loss partials
    int blk = b * 31 + band;   // nblk = 496 across all groups
    float vals[5] = {s_pos, s_neg, s_pl, s_nl, s_reg};
#pragma unroll
    for (int s = 0; s < 5; ++s) {
        redl[t] = vals[s];
        __syncthreads();
        for (int st = 128; st > 0; st >>= 1) {
            if (t < st) redl[t] += redl[t + st];
            __syncthreads();
        }
        if (t == 0) blksums[(size_t)s * 496 + blk] = redl[0];
        __syncthreads();
    }

    // fused finalize: last block overall (fence+atomic) does the fixed-order reduce
    if (t == 0) {
        __threadfence();
        lastflag = (atomicAdd(counter, 1u) == 495u) ? 1u : 0u;
    }
    __syncthreads();
    if (lastflag) {
        __threadfence();
#pragma unroll
        for (int s = 0; s < 5; ++s) {
            float a = 0.f;
            for (int i = t; i < 496; i += 256) a += blksums[(size_t)s * 496 + i];
            redl[t] = a;
            __syncthreads();
            for (int st = 128; st > 0; st >>= 1) {
                if (t < st) redl[t] += redl[t + st];
                __syncthreads();
            }
            if (t == 0) tot[s] = redl[0];
            __syncthreads();
        }
        if (t == 0) {
            float np_ = fmaxf(tot[0], 1.f), nn_ = fmaxf(tot[1], 1.f);
            outp[0] = 0.5f * (tot[2] / np_ + tot[3] / nn_);  // cls_loss
            outp[1] = tot[4] / (np_ * 4.f);                  // reg_loss
        }
    }
}

extern "C" void kernel_launch(void* const* d_in, const int* in_sizes, int n_in,
                              void* d_out, int out_size, void* d_ws, size_t ws_size,
                              hipStream_t stream) {
    (void)in_sizes; (void)n_in; (void)out_size;
    const float* feat   = (const float*)d_in[0];
    const float* gtb    = (const float*)d_in[1];
    const int*   gtc    = (const int*)d_in[2];
    const float* conv_w = (const float*)d_in[3];
    const float* conv_b = (const float*)d_in[4];
    const float* cls_w  = (const float*)d_in[5];
    const float* cls_b  = (const float*)d_in[6];
    const float* box_w  = (const float*)d_in[7];
    const float* box_b  = (const float*)d_in[8];
    float* outp = (float*)d_out;
    float* ws   = (float*)d_ws;

    // workspace layout (floats)
    unsigned short* Bfrag   = (unsigned short*)ws;            // 110592 us = 55296 fl
    float*          effb    = ws + 55296;                     // 64
    float*          maxiou  = ws + 55360;                     // 128
    unsigned int*   counter = (unsigned int*)(ws + 55488);    // 64
    float*          blksums = ws + 55552;                     // 5*496 -> pad 2560
    unsigned short* ft      = (unsigned short*)(ws + 58112);  // g * 1048576 ushorts

    // batch-group size: largest g in {16,8,4,2,1} that fits the workspace
    size_t avail = ws_size / 4;
    int g = 16;
    while (g > 1 && (size_t)58112 + (size_t)g * 524288 > avail) g >>= 1;
    int g0 = g;

    prep_all<<<561 + 256 * g0, 256, 0, stream>>>(feat, conv_w, conv_b, cls_w, cls_b,
                                                 box_w, box_b, gtb, Bfrag, effb, maxiou,
                                                 counter, ft);
    conv_fused<<<31 * g0, 256, 0, stream>>>(ft, Bfrag, effb, gtb, gtc, maxiou,
                                            outp, blksums, counter, 0);
    for (int b0 = g0; b0 < NBAT; b0 += g) {
        to_bf16<<<dim3(32, 8, g), 256, 0, stream>>>(feat, ft, b0);
        conv_fused<<<31 * g, 256, 0, stream>>>(ft, Bfrag, effb, gtb, gtc, maxiou,
                                               outp, blksums, counter, b0);
    }
}

// Round 8
// 80.666 us; speedup vs baseline: 1.4748x; 1.0436x over previous
//
#include <hip/hip_runtime.h>
#include <math.h>

#define HW2   62
#define NANCH 34596   // 62*62*9
#define NBAT  16
#define NGT   8
#define FEATC 256
#define NOUT  45      // 9 cls + 36 box channels

typedef short bf16x8 __attribute__((ext_vector_type(8)));
typedef float f32x4  __attribute__((ext_vector_type(4)));

#define AS1U(p) ((const __attribute__((address_space(1))) unsigned int*)(p))
#define AS3U(p) ((__attribute__((address_space(3))) unsigned int*)(p))

// fp32 -> bf16 round-to-nearest-even
__device__ __forceinline__ unsigned short f2bf(float f) {
    unsigned int u = __float_as_uint(f);
    u = u + 0x7FFFu + ((u >> 16) & 1u);
    return (unsigned short)(u >> 16);
}

// ---------- shared device helpers (bitwise identical to passing R2-R7) ----------

__device__ __forceinline__ void anchor4(int i, int j, int a,
                                        float& x1, float& y1, float& x2, float& y2) {
    int am = a % 3, ad = a / 3;
    float h = 2.f * (float)(am + 1);              // 2,4,6
    float w = h * 0.5f * (float)(1 << ad);        // h*{0.5,1,2}
    float cx = (float)i + 0.5f, cy = (float)j + 0.5f;
    x1 = fminf(fmaxf(cx - 0.5f * w, 0.f), 62.f);
    x2 = fminf(fmaxf(cx + 0.5f * w, 0.f), 62.f);
    y1 = fminf(fmaxf(cy - 0.5f * h, 0.f), 62.f);
    y2 = fminf(fmaxf(cy + 0.5f * h, 0.f), 62.f);
}

__device__ __forceinline__ float iou_fn(float ax1, float ay1, float ax2, float ay2,
                                        float gx1, float gy1, float gx2, float gy2) {
    float area_a = __fmul_rn(__fsub_rn(ax2, ax1), __fsub_rn(ay2, ay1));
    float area_g = __fmul_rn(__fsub_rn(gx2, gx1), __fsub_rn(gy2, gy1));
    float ix1 = fmaxf(ax1, gx1), iy1 = fmaxf(ay1, gy1);
    float ix2 = fminf(ax2, gx2), iy2 = fminf(ay2, gy2);
    float iw = fmaxf(__fsub_rn(ix2, ix1), 0.f);
    float ih = fmaxf(__fsub_rn(iy2, iy1), 0.f);
    float inter = __fmul_rn(iw, ih);
    float uni = __fsub_rn(__fadd_rn(area_a, area_g), inter);
    return inter / fmaxf(uni, 1e-9f);
}

__device__ __forceinline__ float softplus_f(float x) {
    return fmaxf(x, 0.f) + log1pf(expf(-fabsf(x)));
}

__device__ __forceinline__ float sl1_f(float d) {
    float ad = fabsf(d);
    return (ad < 1.f) ? 0.5f * d * d : (ad - 0.5f);
}

// ---------- to_bf16 body: fp32 NCHW -> bf16 [b][cc][cg][y][x][8ch] ----------
__device__ __forceinline__ void to_bf16_body(const float* __restrict__ feat,
                                             unsigned short* __restrict__ ft,
                                             float* ldsT,
                                             int yp, int cc, int bz, int b, int t) {
    int y0 = yp * 2;
#pragma unroll
    for (int k = 0; k < 4; ++k) {
        int fi = k * 256 + t;
        int ch = fi >> 5, r = fi & 31;
        int y = r >> 4, xq = r & 15;
        f32x4 v = *(const f32x4*)(feat + ((size_t)(b * 256 + cc * 32 + ch) << 12)
                                  + (y0 + y) * 64 + xq * 4);
        int word = ch * 128 + y * 64 + ((xq * 4) ^ ((ch & 7) << 3));
        *(f32x4*)(ldsT + word) = v;
    }
    __syncthreads();
    int y = t >> 7, x = (t >> 1) & 63, h2 = t & 1;
    bf16x8 o0, o1;
#pragma unroll
    for (int j = 0; j < 8; ++j) {
        int ch = h2 * 16 + j;
        o0[j] = (short)f2bf(ldsT[ch * 128 + y * 64 + (x ^ ((ch & 7) << 3))]);
    }
#pragma unroll
    for (int j = 0; j < 8; ++j) {
        int ch = h2 * 16 + 8 + j;
        o1[j] = (short)f2bf(ldsT[ch * 128 + y * 64 + (x ^ ((ch & 7) << 3))]);
    }
    unsigned short* ftc = ft + ((size_t)(bz * 8 + cc) << 17);
    size_t p = (size_t)(y0 + y) * 64 + x;
    *(bf16x8*)(ftc + ((size_t)(h2 * 2) * 4096 + p) * 8) = o0;
    *(bf16x8*)(ftc + ((size_t)(h2 * 2 + 1) * 4096 + p) * 8) = o1;
}

// ---------- Kernel 1: prep_all (fold | gt max-iou | effb+counter | to_bf16) ----------
__global__ void prep_all(const float* __restrict__ feat,
                         const float* __restrict__ conv_w,
                         const float* __restrict__ conv_b,
                         const float* __restrict__ cls_w,
                         const float* __restrict__ cls_b,
                         const float* __restrict__ box_w,
                         const float* __restrict__ box_b,
                         const float* __restrict__ gtb,
                         unsigned short* __restrict__ Bfrag,
                         float* __restrict__ effb,
                         float* __restrict__ maxiou,
                         unsigned int* __restrict__ counter,
                         unsigned short* __restrict__ ft) {
    __shared__ float ldsT[4096];
    __shared__ float red[256];
    int blk = blockIdx.x, t = threadIdx.x;
    if (blk < 432) {
        int i = blk * 256 + t;               // < 110592 = 48*2304
        int o = i / 2304, idx = i - o * 2304;
        float s = 0.f;
        if (o < NOUT) {
            const float* w2 = (o < 9) ? (cls_w + o * FEATC) : (box_w + (o - 9) * FEATC);
#pragma unroll 8
            for (int m = 0; m < FEATC; ++m)
                s = fmaf(w2[m], conv_w[(size_t)m * 2304 + idx], s);  // w2 uniform, conv_w coalesced
        }
        int c = idx / 9, tap = idx - c * 9;
        size_t slot = (((size_t)(c >> 5) * 9 + tap) * 3 + (o >> 4)) * 512
                    + (size_t)((((c >> 3) & 3) * 16) + (o & 15)) * 8 + (c & 7);
        Bfrag[slot] = f2bf(s);
    } else if (blk < 560) {
        int bg = blk - 432;
        int b = bg >> 3, g = bg & 7;
        const float* p = gtb + (b * NGT + g) * 4;
        float gx1 = p[0] * 0.125f, gy1 = p[1] * 0.125f;
        float gx2 = p[2] * 0.125f, gy2 = p[3] * 0.125f;
        float m = 0.f;
        for (int n = t; n < NANCH; n += 256) {
            int i = n / 558; int r = n - i * 558; int j = r / 9; int a = r - j * 9;
            float ax1, ay1, ax2, ay2;
            anchor4(i, j, a, ax1, ay1, ax2, ay2);
            m = fmaxf(m, iou_fn(ax1, ay1, ax2, ay2, gx1, gy1, gx2, gy2));
        }
        red[t] = m;
        __syncthreads();
        for (int s = 128; s > 0; s >>= 1) {
            if (t < s) red[t] = fmaxf(red[t], red[t + s]);
            __syncthreads();
        }
        if (t == 0) maxiou[bg] = red[0];
    } else if (blk == 560) {
        if (t == 0) *counter = 0u;
        if (t < 48) {
            float bv = 0.f;
            if (t < NOUT) {
                bv = (t < 9) ? cls_b[t] : box_b[t - 9];
                const float* w2 = (t < 9) ? (cls_w + t * FEATC) : (box_w + (t - 9) * FEATC);
                for (int mid = 0; mid < FEATC; ++mid) bv = fmaf(w2[mid], conv_b[mid], bv);
            }
            effb[t] = bv;
        }
    } else {
        int u = blk - 561;
        int yp = u & 31, cc = (u >> 5) & 7, bz = u >> 8;
        to_bf16_body(feat, ft, ldsT, yp, cc, bz, bz, t);
    }
}

// ---------- standalone to_bf16 for fallback batch groups ----------
__global__ void to_bf16(const float* __restrict__ feat,
                        unsigned short* __restrict__ ft, int b_base) {
    __shared__ float ldsT[4096];
    to_bf16_body(feat, ft, ldsT, blockIdx.x, blockIdx.y, blockIdx.z,
                 b_base + blockIdx.z, threadIdx.x);
}

// ---------- Kernel 2: MFMA conv (A reg-dbuf from global, B LDS-dbuf) + epilogue ----------
// 1D grid nwg = 31*g (bijective XCD swizzle), 256 threads (4 waves).
// Band = 2 output rows. Wave w: pixels w*32..w*32+31 (2 m-frags) x 3 n-frags.
// 8 K-chunks of 32 ch processed as 4 even/odd pairs:
//   chunk cc+1's A-frags are ISSUED (into the other named reg set) before chunk cc's
//   compute and pinned with sched_barrier(0) -> one compute phase + barrier of latency
//   cover; compiler cannot sink the loads (R7's failure mode, VGPR=88 evidence).
__launch_bounds__(256, 2)
__global__ void conv_fused(const unsigned short* __restrict__ ft,
                           const unsigned short* __restrict__ Bfrag,
                           const float* __restrict__ effb,
                           const float* __restrict__ gtb,
                           const int* __restrict__ gtc,
                           const float* __restrict__ maxiou,
                           float* __restrict__ outp,
                           float* __restrict__ blksums,
                           unsigned int* __restrict__ counter,
                           int b_base) {
    __shared__ __align__(16) unsigned char smem[55296];  // B dbuf 2 x 27648; Cs overlays
    __shared__ float gshr[40];
    __shared__ float redl[256];
    __shared__ float tot[5];
    __shared__ unsigned int lastflag;

    float (*Cs)[49] = (float (*)[49])smem;   // 124*49*4 = 24304 B, after K-loop

    const int t = threadIdx.x, l = t & 63, w = t >> 6;
    const int l15 = l & 15, lq = l >> 4;

    // bijective XCD swizzle (m204)
    int nwg = gridDim.x;
    int q = nwg >> 3, r = nwg & 7;
    int xcd = blockIdx.x & 7, within = blockIdx.x >> 3;
    int wgid = ((xcd < r) ? xcd * (q + 1) : r * (q + 1) + (xcd - r) * q) + within;
    const int band = wgid % 31, bz = wgid / 31;
    const int b = b_base + bz;
    const int y0 = band * 2;

    if (t < 32) gshr[t] = gtb[b * 32 + t] * 0.125f;
    else if (t < 40) gshr[t] = maxiou[b * 8 + (t - 32)];

    f32x4 acc[2][3];
#pragma unroll
    for (int nf = 0; nf < 3; ++nf) {
        float bv = effb[nf * 16 + l15];
#pragma unroll
        for (int mf = 0; mf < 2; ++mf)
#pragma unroll
            for (int r2 = 0; r2 < 4; ++r2) acc[mf][nf][r2] = bv;
    }

    // per-thread A base offsets (16B units) into ft chunk; clamp pad pixels
    int p0 = w * 32 + l15;      if (p0 > 123) p0 = 123;
    int p1 = w * 32 + 16 + l15; if (p1 > 123) p1 = 123;
    int rr0 = p0 / 62, c0 = p0 - rr0 * 62;
    int rr1 = p1 / 62, c1 = p1 - rr1 * 62;
    const int aoff0 = (lq << 12) + (y0 + rr0) * 64 + c0;
    const int aoff1 = (lq << 12) + (y0 + rr1) * 64 + c1;

    auto loadB = [&](int cc, int buf) {
        const unsigned short* Bt = Bfrag + (size_t)cc * 13824;
#pragma unroll
        for (int k = 0; k < 7; ++k) {                 // 1728 units of 16B
            int u = t + k * 256;
            if (u < 1728)
                __builtin_amdgcn_global_load_lds(AS1U(Bt + (size_t)u * 8),
                                                 AS3U(smem + buf * 27648 + u * 16), 16, 0, 0);
        }
    };
    // named A register sets (no runtime indexing -> stay in VGPRs)
    bf16x8 Acur0[9], Acur1[9], Anx0[9], Anx1[9];

    auto issueA = [&](int cc, bf16x8 (&d0)[9], bf16x8 (&d1)[9]) {
        const unsigned short* ftc = ft + ((size_t)(bz * 8 + cc) << 17);
#pragma unroll
        for (int tap = 0; tap < 9; ++tap) {
            int d = (tap / 3) * 64 + (tap % 3);
            d0[tap] = *(const bf16x8*)(ftc + (size_t)(aoff0 + d) * 8);
            d1[tap] = *(const bf16x8*)(ftc + (size_t)(aoff1 + d) * 8);
        }
    };
    auto computeChunk = [&](int buf, bf16x8 (&A0)[9], bf16x8 (&A1)[9]) {
        const char* Bb = (const char*)smem + buf * 27648;
#pragma unroll
        for (int tap = 0; tap < 9; ++tap) {
#pragma unroll
            for (int nf = 0; nf < 3; ++nf) {
                bf16x8 bfr = *(const bf16x8*)(Bb + (((tap * 3 + nf) << 6) + l) * 16);
                acc[0][nf] = __builtin_amdgcn_mfma_f32_16x16x32_bf16(A0[tap], bfr, acc[0][nf], 0, 0, 0);
                acc[1][nf] = __builtin_amdgcn_mfma_f32_16x16x32_bf16(A1[tap], bfr, acc[1][nf], 0, 0, 0);
            }
        }
    };

    // prologue: chunk 0 A-regs + B DMA
    issueA(0, Acur0, Acur1);
    loadB(0, 0);
    __syncthreads();   // implicit vmcnt(0) drain: B0 in LDS, A0 in regs

    // 4 even/odd chunk pairs; even chunks use LDS buf0, odd buf1
    for (int ccp = 0; ccp < 4; ++ccp) {
        int cc = ccp * 2;
        // issue next chunk (odd) ahead of even compute
        loadB(cc + 1, 1);
        issueA(cc + 1, Anx0, Anx1);
        __builtin_amdgcn_sched_barrier(0);
        computeChunk(0, Acur0, Acur1);
        __syncthreads();
        // issue chunk cc+2 (even of next pair) ahead of odd compute
        if (ccp < 3) {
            loadB(cc + 2, 0);
            issueA(cc + 2, Acur0, Acur1);
        }
        __builtin_amdgcn_sched_barrier(0);
        computeChunk(1, Anx0, Anx1);
        __syncthreads();
    }

    // C fragments -> LDS (overlays B buffers; safe after final barrier)
#pragma unroll
    for (int mf = 0; mf < 2; ++mf)
#pragma unroll
        for (int nf = 0; nf < 3; ++nf)
#pragma unroll
            for (int r2 = 0; r2 < 4; ++r2) {
                int pix = w * 32 + mf * 16 + lq * 4 + r2;
                if (pix < 124) Cs[pix][nf * 16 + l15] = acc[mf][nf][r2];
            }
    __syncthreads();

    // ---- fused per-anchor epilogue: 2x62 pixels x 9 anchors = 1116 anchors ----
    float s_pos = 0.f, s_neg = 0.f, s_pl = 0.f, s_nl = 0.f, s_reg = 0.f;
    float* out_prop = outp + 2;
    float* out_mask = out_prop + (size_t)NBAT * NANCH * 4;
    float* out_gtc  = out_mask + (size_t)NBAT * NANCH * 8;

    for (int k = 0; k < 5; ++k) {
        int an = k * 256 + t;
        if (an < 1116) {
            int pixloc = an / 9, a = an - pixloc * 9;
            int rr = pixloc / 62, col = pixloc - rr * 62;
            int oy = y0 + rr, ox = col;
            int n = oy * 558 + ox * 9 + a;
            float cls = Cs[pixloc][a];
            float p0f = Cs[pixloc][9 + 4 * a];
            float p1f = Cs[pixloc][10 + 4 * a];
            float p2f = Cs[pixloc][11 + 4 * a];
            float p3f = Cs[pixloc][12 + 4 * a];

            float ax1, ay1, ax2, ay2;
            anchor4(oy, ox, a, ax1, ay1, ax2, ay2);
            float aw = ax2 - ax1, ah = ay2 - ay1;
            float acx = 0.5f * (ax1 + ax2), acy = 0.5f * (ay1 + ay2);

            const float ps = 64.f / 62.f;
            float pcx = acx + p0f * aw, pcy = acy + p1f * ah;
            float pw = aw * expf(p2f), ph = ah * expf(p3f);
            f32x4 prop = { (pcx - 0.5f * pw) * ps, (pcy - 0.5f * ph) * ps,
                           (pcx + 0.5f * pw) * ps, (pcy + 0.5f * ph) * ps };
            *(f32x4*)(out_prop + ((size_t)b * NANCH + n) * 4) = prop;

            float law = logf(aw), lah = logf(ah);
            float posf_tot = 0.f, negf_tot = 0.f;
            float best_iou = -1.f; int best_g = 0;
            float pfv[8];
#pragma unroll
            for (int g = 0; g < NGT; ++g) {
                float gx1 = gshr[g * 4 + 0], gy1 = gshr[g * 4 + 1];
                float gx2 = gshr[g * 4 + 2], gy2 = gshr[g * 4 + 3];
                float iou = iou_fn(ax1, ay1, ax2, ay2, gx1, gy1, gx2, gy2);
                float mpg = gshr[32 + g];
                bool pm = ((iou == mpg) && (mpg > 0.f)) || (iou > 0.7f);
                float pf = pm ? 1.f : 0.f;
                float nf = (iou < 0.3f) ? 1.f : 0.f;
                pfv[g] = pf;
                posf_tot += pf; negf_tot += nf;
                if (iou > best_iou) { best_iou = iou; best_g = g; }  // first-max-wins
                if (pm) {
                    float gw = gx2 - gx1, gh = gy2 - gy1;
                    float gcx = 0.5f * (gx1 + gx2), gcy = 0.5f * (gy1 + gy2);
                    float tx_ = (gcx - acx) / aw, ty_ = (gcy - acy) / ah;
                    float tw_ = logf(gw) - law, th_ = logf(gh) - lah;
                    float d0 = p0f - tx_, d1 = p1f - ty_, d2 = p2f - tw_, d3 = p3f - th_;
                    s_reg += sl1_f(d0) + sl1_f(d1) + sl1_f(d2) + sl1_f(d3);
                }
            }
            size_t mb = ((size_t)b * NANCH + n) * 8;
            f32x4 m0 = { pfv[0], pfv[1], pfv[2], pfv[3] };
            f32x4 m1 = { pfv[4], pfv[5], pfv[6], pfv[7] };
            *(f32x4*)(out_mask + mb) = m0;
            *(f32x4*)(out_mask + mb + 4) = m1;
            s_pos += posf_tot; s_neg += negf_tot;
            s_pl += softplus_f(-cls) * posf_tot;
            s_nl += softplus_f(cls) * negf_tot;
            out_gtc[(size_t)b * NANCH + n] = (float)gtc[b * NGT + best_g];
        }
    }

    // deterministic per-block tree reduction of the 5 loss partials
    int blk = b * 31 + band;   // nblk = 496 across all groups
    float vals[5] = {s_pos, s_neg, s_pl, s_nl, s_reg};
#pragma unroll
    for (int s = 0; s < 5; ++s) {
        redl[t] = vals[s];
        __syncthreads();
        for (int st = 128; st > 0; st >>= 1) {
            if (t < st) redl[t] += redl[t + st];
            __syncthreads();
        }
        if (t == 0) blksums[(size_t)s * 496 + blk] = redl[0];
        __syncthreads();
    }

    // fused finalize: last block overall (fence+atomic) does the fixed-order reduce
    if (t == 0) {
        __threadfence();
        lastflag = (atomicAdd(counter, 1u) == 495u) ? 1u : 0u;
    }
    __syncthreads();
    if (lastflag) {
        __threadfence();
#pragma unroll
        for (int s = 0; s < 5; ++s) {
            float a = 0.f;
            for (int i = t; i < 496; i += 256) a += blksums[(size_t)s * 496 + i];
            redl[t] = a;
            __syncthreads();
            for (int st = 128; st > 0; st >>= 1) {
                if (t < st) redl[t] += redl[t + st];
                __syncthreads();
            }
            if (t == 0) tot[s] = redl[0];
            __syncthreads();
        }
        if (t == 0) {
            float np_ = fmaxf(tot[0], 1.f), nn_ = fmaxf(tot[1], 1.f);
            outp[0] = 0.5f * (tot[2] / np_ + tot[3] / nn_);  // cls_loss
            outp[1] = tot[4] / (np_ * 4.f);                  // reg_loss
        }
    }
}

extern "C" void kernel_launch(void* const* d_in, const int* in_sizes, int n_in,
                              void* d_out, int out_size, void* d_ws, size_t ws_size,
                              hipStream_t stream) {
    (void)in_sizes; (void)n_in; (void)out_size;
    const float* feat   = (const float*)d_in[0];
    const float* gtb    = (const float*)d_in[1];
    const int*   gtc    = (const int*)d_in[2];
    const float* conv_w = (const float*)d_in[3];
    const float* conv_b = (const float*)d_in[4];
    const float* cls_w  = (const float*)d_in[5];
    const float* cls_b  = (const float*)d_in[6];
    const float* box_w  = (const float*)d_in[7];
    const float* box_b  = (const float*)d_in[8];
    float* outp = (float*)d_out;
    float* ws   = (float*)d_ws;

    // workspace layout (floats)
    unsigned short* Bfrag   = (unsigned short*)ws;            // 110592 us = 55296 fl
    float*          effb    = ws + 55296;                     // 64
    float*          maxiou  = ws + 55360;                     // 128
    unsigned int*   counter = (unsigned int*)(ws + 55488);    // 64
    float*          blksums = ws + 55552;                     // 5*496 -> pad 2560
    unsigned short* ft      = (unsigned short*)(ws + 58112);  // g * 1048576 ushorts

    // batch-group size: largest g in {16,8,4,2,1} that fits the workspace
    size_t avail = ws_size / 4;
    int g = 16;
    while (g > 1 && (size_t)58112 + (size_t)g * 524288 > avail) g >>= 1;
    int g0 = g;

    prep_all<<<561 + 256 * g0, 256, 0, stream>>>(feat, conv_w, conv_b, cls_w, cls_b,
                                                 box_w, box_b, gtb, Bfrag, effb, maxiou,
                                                 counter, ft);
    conv_fused<<<31 * g0, 256, 0, stream>>>(ft, Bfrag, effb, gtb, gtc, maxiou,
                                            outp, blksums, counter, 0);
    for (int b0 = g0; b0 < NBAT; b0 += g) {
        to_bf16<<<dim3(32, 8, g), 256, 0, stream>>>(feat, ft, b0);
        conv_fused<<<31 * g, 256, 0, stream>>>(ft, Bfrag, effb, gtb, gtc, maxiou,
                                               outp, blksums, counter, b0);
    }
}

// Round 9
// 73.519 us; speedup vs baseline: 1.6182x; 1.0972x over previous
//
#include <hip/hip_runtime.h>
#include <math.h>

#define HW2   62
#define NANCH 34596   // 62*62*9
#define NBAT  16
#define NGT   8
#define FEATC 256
#define NOUT  45      // 9 cls + 36 box channels

typedef short bf16x8 __attribute__((ext_vector_type(8)));
typedef float f32x4  __attribute__((ext_vector_type(4)));

#define AS1U(p) ((const __attribute__((address_space(1))) unsigned int*)(p))
#define AS3U(p) ((__attribute__((address_space(3))) unsigned int*)(p))

// fp32 -> bf16 round-to-nearest-even
__device__ __forceinline__ unsigned short f2bf(float f) {
    unsigned int u = __float_as_uint(f);
    u = u + 0x7FFFu + ((u >> 16) & 1u);
    return (unsigned short)(u >> 16);
}

// ---------- shared device helpers (bitwise identical to passing R2-R8) ----------

__device__ __forceinline__ void anchor4(int i, int j, int a,
                                        float& x1, float& y1, float& x2, float& y2) {
    int am = a % 3, ad = a / 3;
    float h = 2.f * (float)(am + 1);              // 2,4,6
    float w = h * 0.5f * (float)(1 << ad);        // h*{0.5,1,2}
    float cx = (float)i + 0.5f, cy = (float)j + 0.5f;
    x1 = fminf(fmaxf(cx - 0.5f * w, 0.f), 62.f);
    x2 = fminf(fmaxf(cx + 0.5f * w, 0.f), 62.f);
    y1 = fminf(fmaxf(cy - 0.5f * h, 0.f), 62.f);
    y2 = fminf(fmaxf(cy + 0.5f * h, 0.f), 62.f);
}

__device__ __forceinline__ float iou_fn(float ax1, float ay1, float ax2, float ay2,
                                        float gx1, float gy1, float gx2, float gy2) {
    float area_a = __fmul_rn(__fsub_rn(ax2, ax1), __fsub_rn(ay2, ay1));
    float area_g = __fmul_rn(__fsub_rn(gx2, gx1), __fsub_rn(gy2, gy1));
    float ix1 = fmaxf(ax1, gx1), iy1 = fmaxf(ay1, gy1);
    float ix2 = fminf(ax2, gx2), iy2 = fminf(ay2, gy2);
    float iw = fmaxf(__fsub_rn(ix2, ix1), 0.f);
    float ih = fmaxf(__fsub_rn(iy2, iy1), 0.f);
    float inter = __fmul_rn(iw, ih);
    float uni = __fsub_rn(__fadd_rn(area_a, area_g), inter);
    return inter / fmaxf(uni, 1e-9f);
}

__device__ __forceinline__ float softplus_f(float x) {
    return fmaxf(x, 0.f) + log1pf(expf(-fabsf(x)));
}

__device__ __forceinline__ float sl1_f(float d) {
    float ad = fabsf(d);
    return (ad < 1.f) ? 0.5f * d * d : (ad - 0.5f);
}

// ---------- to_bf16 body: fp32 NCHW -> bf16 [b][cc][cg][y][x][8ch] ----------
__device__ __forceinline__ void to_bf16_body(const float* __restrict__ feat,
                                             unsigned short* __restrict__ ft,
                                             float* ldsT,
                                             int yp, int cc, int bz, int b, int t) {
    int y0 = yp * 2;
#pragma unroll
    for (int k = 0; k < 4; ++k) {
        int fi = k * 256 + t;
        int ch = fi >> 5, r = fi & 31;
        int y = r >> 4, xq = r & 15;
        f32x4 v = *(const f32x4*)(feat + ((size_t)(b * 256 + cc * 32 + ch) << 12)
                                  + (y0 + y) * 64 + xq * 4);
        int word = ch * 128 + y * 64 + ((xq * 4) ^ ((ch & 7) << 3));
        *(f32x4*)(ldsT + word) = v;
    }
    __syncthreads();
    int y = t >> 7, x = (t >> 1) & 63, h2 = t & 1;
    bf16x8 o0, o1;
#pragma unroll
    for (int j = 0; j < 8; ++j) {
        int ch = h2 * 16 + j;
        o0[j] = (short)f2bf(ldsT[ch * 128 + y * 64 + (x ^ ((ch & 7) << 3))]);
    }
#pragma unroll
    for (int j = 0; j < 8; ++j) {
        int ch = h2 * 16 + 8 + j;
        o1[j] = (short)f2bf(ldsT[ch * 128 + y * 64 + (x ^ ((ch & 7) << 3))]);
    }
    unsigned short* ftc = ft + ((size_t)(bz * 8 + cc) << 17);
    size_t p = (size_t)(y0 + y) * 64 + x;
    *(bf16x8*)(ftc + ((size_t)(h2 * 2) * 4096 + p) * 8) = o0;
    *(bf16x8*)(ftc + ((size_t)(h2 * 2 + 1) * 4096 + p) * 8) = o1;
}

// ---------- Kernel 1: prep_all (fold | gt max-iou | effb+counter | to_bf16) ----------
__global__ void prep_all(const float* __restrict__ feat,
                         const float* __restrict__ conv_w,
                         const float* __restrict__ conv_b,
                         const float* __restrict__ cls_w,
                         const float* __restrict__ cls_b,
                         const float* __restrict__ box_w,
                         const float* __restrict__ box_b,
                         const float* __restrict__ gtb,
                         unsigned short* __restrict__ Bfrag,
                         float* __restrict__ effb,
                         float* __restrict__ maxiou,
                         unsigned int* __restrict__ counter,
                         unsigned short* __restrict__ ft) {
    __shared__ float ldsT[4096];
    __shared__ float red[256];
    int blk = blockIdx.x, t = threadIdx.x;
    if (blk < 432) {
        int i = blk * 256 + t;               // < 110592 = 48*2304
        int o = i / 2304, idx = i - o * 2304;
        float s = 0.f;
        if (o < NOUT) {
            const float* w2 = (o < 9) ? (cls_w + o * FEATC) : (box_w + (o - 9) * FEATC);
#pragma unroll 8
            for (int m = 0; m < FEATC; ++m)
                s = fmaf(w2[m], conv_w[(size_t)m * 2304 + idx], s);  // w2 uniform, conv_w coalesced
        }
        int c = idx / 9, tap = idx - c * 9;
        size_t slot = (((size_t)(c >> 5) * 9 + tap) * 3 + (o >> 4)) * 512
                    + (size_t)((((c >> 3) & 3) * 16) + (o & 15)) * 8 + (c & 7);
        Bfrag[slot] = f2bf(s);
    } else if (blk < 560) {
        int bg = blk - 432;
        int b = bg >> 3, g = bg & 7;
        const float* p = gtb + (b * NGT + g) * 4;
        float gx1 = p[0] * 0.125f, gy1 = p[1] * 0.125f;
        float gx2 = p[2] * 0.125f, gy2 = p[3] * 0.125f;
        float m = 0.f;
        for (int n = t; n < NANCH; n += 256) {
            int i = n / 558; int r = n - i * 558; int j = r / 9; int a = r - j * 9;
            float ax1, ay1, ax2, ay2;
            anchor4(i, j, a, ax1, ay1, ax2, ay2);
            m = fmaxf(m, iou_fn(ax1, ay1, ax2, ay2, gx1, gy1, gx2, gy2));
        }
        red[t] = m;
        __syncthreads();
        for (int s = 128; s > 0; s >>= 1) {
            if (t < s) red[t] = fmaxf(red[t], red[t + s]);
            __syncthreads();
        }
        if (t == 0) maxiou[bg] = red[0];
    } else if (blk == 560) {
        if (t == 0) *counter = 0u;
        if (t < 48) {
            float bv = 0.f;
            if (t < NOUT) {
                bv = (t < 9) ? cls_b[t] : box_b[t - 9];
                const float* w2 = (t < 9) ? (cls_w + t * FEATC) : (box_w + (t - 9) * FEATC);
                for (int mid = 0; mid < FEATC; ++mid) bv = fmaf(w2[mid], conv_b[mid], bv);
            }
            effb[t] = bv;
        }
    } else {
        int u = blk - 561;
        int yp = u & 31, cc = (u >> 5) & 7, bz = u >> 8;
        to_bf16_body(feat, ft, ldsT, yp, cc, bz, bz, t);
    }
}

// ---------- standalone to_bf16 for fallback batch groups ----------
__global__ void to_bf16(const float* __restrict__ feat,
                        unsigned short* __restrict__ ft, int b_base) {
    __shared__ float ldsT[4096];
    to_bf16_body(feat, ft, ldsT, blockIdx.x, blockIdx.y, blockIdx.z,
                 b_base + blockIdx.z, threadIdx.x);
}

// ---------- Kernel 2: MFMA conv, HALF-K B staged in LDS, barrier-free K-loop ----------
// grid 16*g blocks (bijective XCD swizzle), 512 threads (8 waves).
// Band = 4 output rows (248 pixels). Wave w: pixels w*32..w*32+31 (2 m-frags x 3 n-frags).
// B: 4 chunks (110.6 KB) staged per half; only 3 barrier-drains in the whole kernel.
__launch_bounds__(512, 2)
__global__ void conv_fused(const unsigned short* __restrict__ ft,
                           const unsigned short* __restrict__ Bfrag,
                           const float* __restrict__ effb,
                           const float* __restrict__ gtb,
                           const int* __restrict__ gtc,
                           const float* __restrict__ maxiou,
                           float* __restrict__ outp,
                           float* __restrict__ blksums,
                           unsigned int* __restrict__ counter,
                           int b_base) {
    __shared__ __align__(16) unsigned char smem[110592];  // B half (4 x 27648); Cs overlays
    __shared__ float gshr[40];
    __shared__ float redl[512];
    __shared__ float tot[5];
    __shared__ unsigned int lastflag;

    float (*Cs)[49] = (float (*)[49])smem;   // 248*49*4 = 48608 B, after K-loop

    const int t = threadIdx.x, l = t & 63, w = t >> 6;
    const int l15 = l & 15, lq = l >> 4;

    // bijective XCD swizzle (m204)
    int nwg = gridDim.x;
    int q = nwg >> 3, r = nwg & 7;
    int xcd = blockIdx.x & 7, within = blockIdx.x >> 3;
    int wgid = ((xcd < r) ? xcd * (q + 1) : r * (q + 1) + (xcd - r) * q) + within;
    const int band = wgid & 15, bz = wgid >> 4;
    const int b = b_base + bz;
    const int y0 = band * 4;

    if (t < 32) gshr[t] = gtb[b * 32 + t] * 0.125f;
    else if (t < 40) gshr[t] = maxiou[b * 8 + (t - 32)];

    f32x4 acc[2][3];
#pragma unroll
    for (int nf = 0; nf < 3; ++nf) {
        float bv = effb[nf * 16 + l15];
#pragma unroll
        for (int mf = 0; mf < 2; ++mf)
#pragma unroll
            for (int r2 = 0; r2 < 4; ++r2) acc[mf][nf][r2] = bv;
    }

    // A-frag (row, col) per m-frag; rows clamped per-tap below (band 15 pad safety)
    int p0 = w * 32 + l15;      if (p0 > 247) p0 = 247;
    int p1 = w * 32 + 16 + l15; if (p1 > 247) p1 = 247;
    int rr0 = p0 / 62, c0 = p0 - rr0 * 62;
    int rr1 = p1 / 62, c1 = p1 - rr1 * 62;
    // per-dy row-clamped bases (16B units): (lq<<12) + min(y0+rr+dy,63)*64 + c
    int ab0[3], ab1[3];
#pragma unroll
    for (int dy = 0; dy < 3; ++dy) {
        int ya = y0 + rr0 + dy; if (ya > 63) ya = 63;
        int yb = y0 + rr1 + dy; if (yb > 63) yb = 63;
        ab0[dy] = (lq << 12) + ya * 64 + c0;
        ab1[dy] = (lq << 12) + yb * 64 + c1;
    }

    auto stageBhalf = [&](int h) {
        const unsigned short* Bt = Bfrag + (size_t)h * 55296;   // 4 chunks contiguous
#pragma unroll
        for (int k = 0; k < 14; ++k) {                          // 6912 units of 16B
            int u = t + k * 512;
            if (u < 6912)
                __builtin_amdgcn_global_load_lds(AS1U(Bt + (size_t)u * 8),
                                                 AS3U(smem + u * 16), 16, 0, 0);
        }
    };
    // one 32-ch chunk: 18 A global loads (hoistable freely: NO barriers around)
    auto computeChunk = [&](int ccg, int ccl) {
        const unsigned short* ftc = ft + ((size_t)(bz * 8 + ccg) << 17);
        bf16x8 A0[9], A1[9];
#pragma unroll
        for (int dy = 0; dy < 3; ++dy)
#pragma unroll
            for (int dx = 0; dx < 3; ++dx) {
                A0[dy * 3 + dx] = *(const bf16x8*)(ftc + (size_t)(ab0[dy] + dx) * 8);
                A1[dy * 3 + dx] = *(const bf16x8*)(ftc + (size_t)(ab1[dy] + dx) * 8);
            }
        const char* Bb = (const char*)smem + ccl * 27648;
#pragma unroll
        for (int tap = 0; tap < 9; ++tap) {
#pragma unroll
            for (int nf = 0; nf < 3; ++nf) {
                bf16x8 bfr = *(const bf16x8*)(Bb + (((tap * 3 + nf) << 6) + l) * 16);
                acc[0][nf] = __builtin_amdgcn_mfma_f32_16x16x32_bf16(A0[tap], bfr, acc[0][nf], 0, 0, 0);
                acc[1][nf] = __builtin_amdgcn_mfma_f32_16x16x32_bf16(A1[tap], bfr, acc[1][nf], 0, 0, 0);
            }
        }
    };

    // half 0
    stageBhalf(0);
    __syncthreads();                     // drain 1: B half 0 resident
    computeChunk(0, 0);
    computeChunk(1, 1);
    computeChunk(2, 2);
    computeChunk(3, 3);
    __syncthreads();                     // all waves done reading half-0 LDS
    // half 1
    stageBhalf(1);
    __syncthreads();                     // drain 2: B half 1 resident
    computeChunk(4, 0);
    computeChunk(5, 1);
    computeChunk(6, 2);
    computeChunk(7, 3);
    __syncthreads();                     // drain 3: done; Cs may overlay

    // C fragments -> LDS
#pragma unroll
    for (int mf = 0; mf < 2; ++mf)
#pragma unroll
        for (int nf = 0; nf < 3; ++nf)
#pragma unroll
            for (int r2 = 0; r2 < 4; ++r2) {
                int pix = w * 32 + mf * 16 + lq * 4 + r2;
                if (pix < 248) Cs[pix][nf * 16 + l15] = acc[mf][nf][r2];
            }
    __syncthreads();

    // ---- fused per-anchor epilogue: 4x62 pixels x 9 anchors = 2232 anchors ----
    float s_pos = 0.f, s_neg = 0.f, s_pl = 0.f, s_nl = 0.f, s_reg = 0.f;
    float* out_prop = outp + 2;
    float* out_mask = out_prop + (size_t)NBAT * NANCH * 4;
    float* out_gtc  = out_mask + (size_t)NBAT * NANCH * 8;

    for (int k = 0; k < 5; ++k) {
        int an = k * 512 + t;
        if (an < 2232) {
            int pixloc = an / 9, a = an - pixloc * 9;
            int rr = pixloc / 62, col = pixloc - rr * 62;
            int oy = y0 + rr, ox = col;
            if (oy < HW2) {
                int n = oy * 558 + ox * 9 + a;
                float cls = Cs[pixloc][a];
                float p0f = Cs[pixloc][9 + 4 * a];
                float p1f = Cs[pixloc][10 + 4 * a];
                float p2f = Cs[pixloc][11 + 4 * a];
                float p3f = Cs[pixloc][12 + 4 * a];

                float ax1, ay1, ax2, ay2;
                anchor4(oy, ox, a, ax1, ay1, ax2, ay2);
                float aw = ax2 - ax1, ah = ay2 - ay1;
                float acx = 0.5f * (ax1 + ax2), acy = 0.5f * (ay1 + ay2);

                const float ps = 64.f / 62.f;
                float pcx = acx + p0f * aw, pcy = acy + p1f * ah;
                float pw = aw * expf(p2f), ph = ah * expf(p3f);
                f32x4 prop = { (pcx - 0.5f * pw) * ps, (pcy - 0.5f * ph) * ps,
                               (pcx + 0.5f * pw) * ps, (pcy + 0.5f * ph) * ps };
                *(f32x4*)(out_prop + ((size_t)b * NANCH + n) * 4) = prop;

                float law = logf(aw), lah = logf(ah);
                float posf_tot = 0.f, negf_tot = 0.f;
                float best_iou = -1.f; int best_g = 0;
                float pfv[8];
#pragma unroll
                for (int g = 0; g < NGT; ++g) {
                    float gx1 = gshr[g * 4 + 0], gy1 = gshr[g * 4 + 1];
                    float gx2 = gshr[g * 4 + 2], gy2 = gshr[g * 4 + 3];
                    float iou = iou_fn(ax1, ay1, ax2, ay2, gx1, gy1, gx2, gy2);
                    float mpg = gshr[32 + g];
                    bool pm = ((iou == mpg) && (mpg > 0.f)) || (iou > 0.7f);
                    float pf = pm ? 1.f : 0.f;
                    float nf = (iou < 0.3f) ? 1.f : 0.f;
                    pfv[g] = pf;
                    posf_tot += pf; negf_tot += nf;
                    if (iou > best_iou) { best_iou = iou; best_g = g; }  // first-max-wins
                    if (pm) {
                        float gw = gx2 - gx1, gh = gy2 - gy1;
                        float gcx = 0.5f * (gx1 + gx2), gcy = 0.5f * (gy1 + gy2);
                        float tx_ = (gcx - acx) / aw, ty_ = (gcy - acy) / ah;
                        float tw_ = logf(gw) - law, th_ = logf(gh) - lah;
                        float d0 = p0f - tx_, d1 = p1f - ty_, d2 = p2f - tw_, d3 = p3f - th_;
                        s_reg += sl1_f(d0) + sl1_f(d1) + sl1_f(d2) + sl1_f(d3);
                    }
                }
                size_t mb = ((size_t)b * NANCH + n) * 8;
                f32x4 m0 = { pfv[0], pfv[1], pfv[2], pfv[3] };
                f32x4 m1 = { pfv[4], pfv[5], pfv[6], pfv[7] };
                *(f32x4*)(out_mask + mb) = m0;
                *(f32x4*)(out_mask + mb + 4) = m1;
                s_pos += posf_tot; s_neg += negf_tot;
                s_pl += softplus_f(-cls) * posf_tot;
                s_nl += softplus_f(cls) * negf_tot;
                out_gtc[(size_t)b * NANCH + n] = (float)gtc[b * NGT + best_g];
            }
        }
    }

    // deterministic per-block tree reduction of the 5 loss partials
    int blk = b * 16 + band;   // nblk = 256 across all groups
    float vals[5] = {s_pos, s_neg, s_pl, s_nl, s_reg};
#pragma unroll
    for (int s = 0; s < 5; ++s) {
        redl[t] = vals[s];
        __syncthreads();
        for (int st = 256; st > 0; st >>= 1) {
            if (t < st) redl[t] += redl[t + st];
            __syncthreads();
        }
        if (t == 0) blksums[(size_t)s * 256 + blk] = redl[0];
        __syncthreads();
    }

    // fused finalize: last block overall (fence+atomic) does the fixed-order reduce
    if (t == 0) {
        __threadfence();
        lastflag = (atomicAdd(counter, 1u) == 255u) ? 1u : 0u;
    }
    __syncthreads();
    if (lastflag) {
        __threadfence();
#pragma unroll
        for (int s = 0; s < 5; ++s) {
            redl[t] = (t < 256) ? blksums[(size_t)s * 256 + t] : 0.f;
            __syncthreads();
            for (int st = 256; st > 0; st >>= 1) {
                if (t < st) redl[t] += redl[t + st];
                __syncthreads();
            }
            if (t == 0) tot[s] = redl[0];
            __syncthreads();
        }
        if (t == 0) {
            float np_ = fmaxf(tot[0], 1.f), nn_ = fmaxf(tot[1], 1.f);
            outp[0] = 0.5f * (tot[2] / np_ + tot[3] / nn_);  // cls_loss
            outp[1] = tot[4] / (np_ * 4.f);                  // reg_loss
        }
    }
}

extern "C" void kernel_launch(void* const* d_in, const int* in_sizes, int n_in,
                              void* d_out, int out_size, void* d_ws, size_t ws_size,
                              hipStream_t stream) {
    (void)in_sizes; (void)n_in; (void)out_size;
    const float* feat   = (const float*)d_in[0];
    const float* gtb    = (const float*)d_in[1];
    const int*   gtc    = (const int*)d_in[2];
    const float* conv_w = (const float*)d_in[3];
    const float* conv_b = (const float*)d_in[4];
    const float* cls_w  = (const float*)d_in[5];
    const float* cls_b  = (const float*)d_in[6];
    const float* box_w  = (const float*)d_in[7];
    const float* box_b  = (const float*)d_in[8];
    float* outp = (float*)d_out;
    float* ws   = (float*)d_ws;

    // workspace layout (floats)
    unsigned short* Bfrag   = (unsigned short*)ws;            // 110592 us = 55296 fl
    float*          effb    = ws + 55296;                     // 64
    float*          maxiou  = ws + 55360;                     // 128
    unsigned int*   counter = (unsigned int*)(ws + 55488);    // 64
    float*          blksums = ws + 55552;                     // 5*256 -> pad 2560
    unsigned short* ft      = (unsigned short*)(ws + 58112);  // g * 1048576 ushorts

    // batch-group size: largest g in {16,8,4,2,1} that fits the workspace
    size_t avail = ws_size / 4;
    int g = 16;
    while (g > 1 && (size_t)58112 + (size_t)g * 524288 > avail) g >>= 1;
    int g0 = g;

    prep_all<<<561 + 256 * g0, 256, 0, stream>>>(feat, conv_w, conv_b, cls_w, cls_b,
                                                 box_w, box_b, gtb, Bfrag, effb, maxiou,
                                                 counter, ft);
    conv_fused<<<16 * g0, 512, 0, stream>>>(ft, Bfrag, effb, gtb, gtc, maxiou,
                                            outp, blksums, counter, 0);
    for (int b0 = g0; b0 < NBAT; b0 += g) {
        to_bf16<<<dim3(32, 8, g), 256, 0, stream>>>(feat, ft, b0);
        conv_fused<<<16 * g, 512, 0, stream>>>(ft, Bfrag, effb, gtb, gtc, maxiou,
                                               outp, blksums, counter, b0);
    }
}